// Round 1
// baseline (844.401 us; speedup 1.0000x reference)
//
#include <hip/hip_runtime.h>

#define NB 2048
#define S_LEN 64
#define H_LEN 256
#define DIM 256
#define NULL_ATT (-4194304.0f)

__global__ __launch_bounds__(256, 2) void coatt_fused(
    const float* __restrict__ item_emb,    // [B,256]
    const float* __restrict__ x_session,   // [B,64,256]
    const int*   __restrict__ session_len, // [B]
    const float* __restrict__ user_hist,   // [B,256,256]
    const int*   __restrict__ hist_len,    // [B]
    const float* __restrict__ W1,          // [256,512] row-major (j,k)
    const float* __restrict__ b1,          // [256]
    float* __restrict__ out)               // [B*256 rep | B*256 score]
{
    const int b = blockIdx.x;
    const int t = threadIdx.x;
    const int sl = session_len[b];
    const int hl = hist_len[b];

    __shared__ __align__(16) float q[S_LEN][DIM];   // 64 KB query tile
    __shared__ float sMax[2][H_LEN];                // per-s-half max
    __shared__ float red[256];
    __shared__ float wts[256];

    // ---- Phase 0: item part of query for column j=t (kept in register) ----
    float iq;
    {
        float acc = b1[t];
        const float* wrow = W1 + (size_t)t * 512;
        const float* irow = item_emb + (size_t)b * 256;
        #pragma unroll 8
        for (int k = 0; k < 256; k += 4) {
            float4 w4 = *(const float4*)(wrow + k);
            float4 i4 = *(const float4*)(irow + k);   // uniform address -> s_load
            acc += w4.x * i4.x + w4.y * i4.y + w4.z * i4.z + w4.w * i4.w;
        }
        iq = acc;
    }

    // ---- Phase 1: query tile q[s][t] for s-chunks overlapping [0, sl) ----
    {
        const float* wrow = W1 + (size_t)t * 512 + 256;
        for (int c = 0; c < 4; ++c) {
            if (c * 16 >= sl) break;   // uniform across block
            const float* xbase = x_session + ((size_t)b * 64 + (size_t)c * 16) * 256;
            float acc[16];
            #pragma unroll
            for (int si = 0; si < 16; ++si) acc[si] = iq;
            for (int k = 0; k < 256; k += 4) {
                float4 w4 = *(const float4*)(wrow + k);
                #pragma unroll
                for (int si = 0; si < 16; ++si) {
                    float4 x4 = *(const float4*)(xbase + si * 256 + k); // uniform -> s_load
                    acc[si] += w4.x * x4.x + w4.y * x4.y + w4.z * x4.z + w4.w * x4.w;
                }
            }
            #pragma unroll
            for (int si = 0; si < 16; ++si) q[c * 16 + si][t] = acc[si];
        }
    }
    sMax[0][t] = NULL_ATT;
    sMax[1][t] = NULL_ATT;
    __syncthreads();

    // ---- Phase 2: att = q @ hist^T, masked max over s ----
    {
        const int shalf = t >> 7;          // 0: s in [0,32), 1: s in [32,64)
        const int hpair = t & 127;
        const int h0 = hpair * 2;
        const int h1 = h0 + 1;
        const int sbase = shalf * 32;
        const bool active = (h0 < hl) && (sbase < sl);
        if (active) {
            float a0[32], a1[32];
            #pragma unroll
            for (int si = 0; si < 32; ++si) { a0[si] = 0.f; a1[si] = 0.f; }
            const float* h0p = user_hist + ((size_t)b * 256 + (size_t)h0) * 256;
            const float* h1p = h0p + 256;
            for (int k = 0; k < 256; k += 4) {
                float4 hv0 = *(const float4*)(h0p + k);
                float4 hv1 = *(const float4*)(h1p + k);
                #pragma unroll
                for (int si = 0; si < 32; ++si) {
                    float4 q4 = *(const float4*)(&q[sbase + si][k]); // wave-uniform -> LDS broadcast
                    a0[si] += q4.x * hv0.x + q4.y * hv0.y + q4.z * hv0.z + q4.w * hv0.w;
                    a1[si] += q4.x * hv1.x + q4.y * hv1.y + q4.z * hv1.z + q4.w * hv1.w;
                }
            }
            float m0 = NULL_ATT, m1 = NULL_ATT;
            #pragma unroll
            for (int si = 0; si < 32; ++si) {
                if (sbase + si < sl) {
                    m0 = fmaxf(m0, a0[si]);
                    m1 = fmaxf(m1, a1[si]);
                }
            }
            sMax[shalf][h0] = m0;
            if (h1 < hl) sMax[shalf][h1] = m1;
        }
    }
    __syncthreads();

    // ---- Phase 3: score + exact softmax over h ----
    float sc = fmaxf(sMax[0][t], sMax[1][t]);
    out[(size_t)NB * DIM + (size_t)b * 256 + t] = sc;   // score output

    red[t] = sc;
    __syncthreads();
    #pragma unroll
    for (int off = 128; off >= 1; off >>= 1) {
        if (t < off) red[t] = fmaxf(red[t], red[t + off]);
        __syncthreads();
    }
    const float m = red[0];
    __syncthreads();
    const float e = expf(sc - m);   // all-NULL case: exp(0)=1 -> uniform weights
    red[t] = e;
    __syncthreads();
    #pragma unroll
    for (int off = 128; off >= 1; off >>= 1) {
        if (t < off) red[t] += red[t + off];
        __syncthreads();
    }
    const float ssum = red[0];
    __syncthreads();
    wts[t] = e / ssum;
    __syncthreads();

    // ---- Phase 4: weighted history sum, column j=t ----
    const int hcount = (m == NULL_ATT) ? 256 : hl;  // w[h]=0 exactly for h>=hl otherwise
    const float* hb = user_hist + (size_t)b * 256 * 256 + t;
    float r0 = 0.f, r1 = 0.f, r2 = 0.f, r3 = 0.f;
    int h = 0;
    for (; h + 4 <= hcount; h += 4) {
        r0 += wts[h + 0] * hb[(size_t)(h + 0) * 256];
        r1 += wts[h + 1] * hb[(size_t)(h + 1) * 256];
        r2 += wts[h + 2] * hb[(size_t)(h + 2) * 256];
        r3 += wts[h + 3] * hb[(size_t)(h + 3) * 256];
    }
    for (; h < hcount; ++h) r0 += wts[h] * hb[(size_t)h * 256];
    out[(size_t)b * 256 + t] = (r0 + r1) + (r2 + r3);
}

extern "C" void kernel_launch(void* const* d_in, const int* in_sizes, int n_in,
                              void* d_out, int out_size, void* d_ws, size_t ws_size,
                              hipStream_t stream) {
    const float* item_emb    = (const float*)d_in[0];
    const float* x_session   = (const float*)d_in[1];
    const int*   session_len = (const int*)d_in[2];
    const float* user_hist   = (const float*)d_in[3];
    const int*   hist_len    = (const int*)d_in[4];
    const float* W1          = (const float*)d_in[5];
    const float* b1          = (const float*)d_in[6];
    float* out = (float*)d_out;

    coatt_fused<<<NB, 256, 0, stream>>>(item_emb, x_session, session_len,
                                        user_hist, hist_len, W1, b1, out);
}

// Round 2
// 325.388 us; speedup vs baseline: 2.5951x; 2.5951x over previous
//
#include <hip/hip_runtime.h>

#define NB 2048
#define S_LEN 64
#define H_LEN 256
#define DIM 256
#define NULL_ATT (-4194304.0f)

typedef __attribute__((ext_vector_type(8))) short bf16x8;
typedef __attribute__((ext_vector_type(4))) float f32x4;

// swizzled element offset into a [64][256] short LDS array.
// granule = 8 shorts (16B); XOR with (s&7) spreads the 16 rows of an MFMA
// A-frag read across 8 distinct 16B slots -> 2-way (free) instead of 16-way.
__device__ __forceinline__ int qoff(int s, int k) {
    int g = k >> 3;
    return s * 256 + (((g ^ (s & 7)) << 3) | (k & 7));
}

// exact split: f == hi + lo (hi = truncate-to-bf16, lo = exact residual)
__device__ __forceinline__ void cvt8(const float* __restrict__ p, bf16x8& hi, bf16x8& lo) {
    float4 v0 = *(const float4*)p;
    float4 v1 = *(const float4*)(p + 4);
    float f[8] = {v0.x, v0.y, v0.z, v0.w, v1.x, v1.y, v1.z, v1.w};
    #pragma unroll
    for (int j = 0; j < 8; ++j) {
        unsigned u = __builtin_bit_cast(unsigned, f[j]);
        float fh = __builtin_bit_cast(float, u & 0xFFFF0000u);
        float fl = f[j] - fh;                       // exact
        hi[j] = (short)(u >> 16);
        lo[j] = (short)(__builtin_bit_cast(unsigned, fl) >> 16);  // exact repr
    }
}

__device__ __forceinline__ f32x4 mac3(bf16x8 ah, bf16x8 al, bf16x8 bh, bf16x8 bl, f32x4 c) {
    c = __builtin_amdgcn_mfma_f32_16x16x32_bf16(ah, bh, c, 0, 0, 0);
    c = __builtin_amdgcn_mfma_f32_16x16x32_bf16(ah, bl, c, 0, 0, 0);
    c = __builtin_amdgcn_mfma_f32_16x16x32_bf16(al, bh, c, 0, 0, 0);
    return c;
}

__global__ __launch_bounds__(256, 2) void coatt_fused(
    const float* __restrict__ item_emb,    // [B,256]
    const float* __restrict__ x_session,   // [B,64,256]
    const int*   __restrict__ session_len, // [B]
    const float* __restrict__ user_hist,   // [B,256,256]
    const int*   __restrict__ hist_len,    // [B]
    const float* __restrict__ W1,          // [256,512] row-major
    const float* __restrict__ b1,          // [256]
    float* __restrict__ out)               // [B*256 rep | B*256 score]
{
    const int b = blockIdx.x;
    const int t = threadIdx.x;
    const int wave = t >> 6;
    const int lane = t & 63;
    const int lr  = lane & 15;   // tile row/col selector
    const int lo8 = lane >> 4;   // k-octet selector
    const int sl = session_len[b];
    const int hl = hist_len[b];

    __shared__ __align__(16) short qh[64 * 256];   // 32 KB query hi
    __shared__ __align__(16) short ql[64 * 256];   // 32 KB query lo
    __shared__ float iqs[256];
    __shared__ float sMax[256];
    __shared__ float red[256];
    __shared__ float wts[256];

    // ---- Phase 0: item part of query, iq[j=t] (matvec, VALU) ----
    {
        float acc = b1[t];
        const float* wrow = W1 + (size_t)t * 512;
        const float* irow = item_emb + (size_t)b * 256;
        #pragma unroll 8
        for (int k = 0; k < 256; k += 4) {
            float4 w4 = *(const float4*)(wrow + k);
            float4 i4 = *(const float4*)(irow + k);   // uniform -> s_load
            acc += w4.x * i4.x + w4.y * i4.y + w4.z * i4.z + w4.w * i4.w;
        }
        iqs[t] = acc;
    }
    sMax[t] = NULL_ATT;
    __syncthreads();

    const int nst = (sl + 15) >> 4;   // active s-tiles (0..4), block-uniform

    // ---- Phase 1 (MFMA): q[s][j] = iq[j] + x_session[s][:] @ W1[j][256:512] ----
    if (sl > 0) {
        const int jb = wave * 64;
        f32x4 acc[4][4];
        #pragma unroll
        for (int jt = 0; jt < 4; ++jt) {
            float v = iqs[jb + jt * 16 + lr];
            f32x4 iv = {v, v, v, v};
            #pragma unroll
            for (int st = 0; st < 4; ++st) acc[st][jt] = iv;
        }
        const float* xbase = x_session + (size_t)b * 64 * 256;
        for (int kc = 0; kc < 8; ++kc) {
            bf16x8 ah[4], al[4];
            #pragma unroll
            for (int st = 0; st < 4; ++st) {
                if (st < nst)
                    cvt8(xbase + (size_t)(st * 16 + lr) * 256 + kc * 32 + lo8 * 8,
                         ah[st], al[st]);
            }
            #pragma unroll
            for (int jt = 0; jt < 4; ++jt) {
                bf16x8 bh, bl;
                cvt8(W1 + (size_t)(jb + jt * 16 + lr) * 512 + 256 + kc * 32 + lo8 * 8,
                     bh, bl);
                #pragma unroll
                for (int st = 0; st < 4; ++st)
                    if (st < nst) acc[st][jt] = mac3(ah[st], al[st], bh, bl, acc[st][jt]);
            }
        }
        // store q tile to LDS as hi/lo with swizzle
        #pragma unroll
        for (int st = 0; st < 4; ++st) {
            if (st < nst) {
                #pragma unroll
                for (int jt = 0; jt < 4; ++jt) {
                    int j = jb + jt * 16 + lr;
                    #pragma unroll
                    for (int i = 0; i < 4; ++i) {
                        int s = st * 16 + lo8 * 4 + i;
                        float f = acc[st][jt][i];
                        unsigned u = __builtin_bit_cast(unsigned, f);
                        float fh = __builtin_bit_cast(float, u & 0xFFFF0000u);
                        int o = qoff(s, j);
                        qh[o] = (short)(u >> 16);
                        ql[o] = (short)(__builtin_bit_cast(unsigned, f - fh) >> 16);
                    }
                }
            }
        }
    }
    __syncthreads();

    // ---- Phase 2 (MFMA): att[s][h] = q[s][:] @ hist[h][:], masked max -> score ----
    if (sl > 0 && hl > 0) {
        const int hb = wave * 64;
        const int nht = (hl - hb + 15) >> 4;   // wave-uniform; <=0 -> skip
        f32x4 acc[4][4];                        // [st][ht]
        #pragma unroll
        for (int st = 0; st < 4; ++st)
            #pragma unroll
            for (int ht = 0; ht < 4; ++ht) acc[st][ht] = f32x4{0.f, 0.f, 0.f, 0.f};

        const float* hbase = user_hist + (size_t)b * 256 * 256;
        for (int kc = 0; kc < 8; ++kc) {
            bf16x8 ah[4], al[4];
            #pragma unroll
            for (int st = 0; st < 4; ++st) {
                if (st < nst) {
                    int o = qoff(st * 16 + lr, kc * 32 + lo8 * 8);
                    ah[st] = *(const bf16x8*)&qh[o];
                    al[st] = *(const bf16x8*)&ql[o];
                }
            }
            #pragma unroll
            for (int ht = 0; ht < 4; ++ht) {
                if (ht < nht) {
                    bf16x8 bh, bl;
                    cvt8(hbase + (size_t)(hb + ht * 16 + lr) * 256 + kc * 32 + lo8 * 8,
                         bh, bl);
                    #pragma unroll
                    for (int st = 0; st < 4; ++st)
                        if (st < nst) acc[st][ht] = mac3(ah[st], al[st], bh, bl, acc[st][ht]);
                }
            }
        }
        // masked max over s, reduce across lane groups (same h in lanes l, l^16, l^32)
        #pragma unroll
        for (int ht = 0; ht < 4; ++ht) {
            if (ht < nht) {
                float m = NULL_ATT;
                #pragma unroll
                for (int st = 0; st < 4; ++st) {
                    if (st < nst) {
                        #pragma unroll
                        for (int i = 0; i < 4; ++i) {
                            int s = st * 16 + lo8 * 4 + i;
                            if (s < sl) m = fmaxf(m, acc[st][ht][i]);
                        }
                    }
                }
                m = fmaxf(m, __shfl_xor(m, 16, 64));
                m = fmaxf(m, __shfl_xor(m, 32, 64));
                int h = hb + ht * 16 + lr;
                if (lane < 16 && h < hl) sMax[h] = m;
            }
        }
    }
    __syncthreads();

    // ---- Phase 3: score out + exact softmax over h ----
    float sc = sMax[t];
    out[(size_t)NB * DIM + (size_t)b * 256 + t] = sc;

    red[t] = sc;
    __syncthreads();
    #pragma unroll
    for (int off = 128; off >= 1; off >>= 1) {
        if (t < off) red[t] = fmaxf(red[t], red[t + off]);
        __syncthreads();
    }
    const float m = red[0];
    __syncthreads();
    const float e = expf(sc - m);   // all-NULL case: exp(0)=1 -> uniform
    red[t] = e;
    __syncthreads();
    #pragma unroll
    for (int off = 128; off >= 1; off >>= 1) {
        if (t < off) red[t] += red[t + off];
        __syncthreads();
    }
    const float ssum = red[0];
    __syncthreads();
    wts[t] = e / ssum;
    __syncthreads();

    // ---- Phase 4: weighted history sum, column j=t (coalesced) ----
    const int hcount = (m == NULL_ATT) ? 256 : hl;  // w[h]=0 exactly for h>=hl otherwise
    const float* hb4 = user_hist + (size_t)b * 256 * 256 + t;
    float r0 = 0.f, r1 = 0.f, r2 = 0.f, r3 = 0.f;
    int h = 0;
    for (; h + 4 <= hcount; h += 4) {
        r0 += wts[h + 0] * hb4[(size_t)(h + 0) * 256];
        r1 += wts[h + 1] * hb4[(size_t)(h + 1) * 256];
        r2 += wts[h + 2] * hb4[(size_t)(h + 2) * 256];
        r3 += wts[h + 3] * hb4[(size_t)(h + 3) * 256];
    }
    for (; h < hcount; ++h) r0 += wts[h] * hb4[(size_t)h * 256];
    out[(size_t)b * 256 + t] = (r0 + r1) + (r2 + r3);
}

extern "C" void kernel_launch(void* const* d_in, const int* in_sizes, int n_in,
                              void* d_out, int out_size, void* d_ws, size_t ws_size,
                              hipStream_t stream) {
    const float* item_emb    = (const float*)d_in[0];
    const float* x_session   = (const float*)d_in[1];
    const int*   session_len = (const int*)d_in[2];
    const float* user_hist   = (const float*)d_in[3];
    const int*   hist_len    = (const int*)d_in[4];
    const float* W1          = (const float*)d_in[5];
    const float* b1          = (const float*)d_in[6];
    float* out = (float*)d_out;

    coatt_fused<<<NB, 256, 0, stream>>>(item_emb, x_session, session_len,
                                        user_hist, hist_len, W1, b1, out);
}